// Round 13
// baseline (227.958 us; speedup 1.0000x reference)
//
#include <hip/hip_runtime.h>
#include <math.h>

typedef __attribute__((ext_vector_type(8))) short short8;
typedef __attribute__((ext_vector_type(4))) float float4v;
typedef __attribute__((ext_vector_type(4))) unsigned short ushort4v;

static __device__ __forceinline__ unsigned short f2bf(float f) {
    union { float f; unsigned u; } v; v.f = f;
    unsigned u = v.u;
    return (unsigned short)((u + 0x7fffu + ((u >> 16) & 1u)) >> 16);
}
static __device__ __forceinline__ float bf2f(unsigned short h) {
    union { unsigned u; float f; } v; v.u = ((unsigned)h) << 16;
    return v.f;
}
static __device__ __forceinline__ unsigned pk2(float a, float b) {
    return (unsigned)f2bf(a) | ((unsigned)f2bf(b) << 16);
}

// ---------------------------------------------------------------------------
// Graph structure (compile-time), matching Python enumeration order.
// ---------------------------------------------------------------------------
struct AdjT {
    int src[120];
    int dst[120];
    int cnt[36];
    int idx[36][4];
    int ostart[36];
    int ocnt[36];
};

constexpr AdjT build_adj() {
    AdjT a{};
    const int ddx[4] = {-1, 0, 0, 1};
    const int ddy[4] = {0, -1, 1, 0};
    int ne = 0;
    for (int i = 0; i < 6; i++)
        for (int j = 0; j < 6; j++)
            for (int d = 0; d < 4; d++) {
                int x = i + ddx[d], y = j + ddy[d];
                if (x >= 0 && x < 6 && y >= 0 && y < 6) {
                    a.src[ne] = j * 6 + i;
                    a.dst[ne] = y * 6 + x;
                    ne++;
                }
            }
    for (int n = 0; n < 36; n++) {
        a.cnt[n] = 0;
        for (int e = 0; e < 120; e++)
            if (a.dst[e] == n) a.idx[n][a.cnt[n]++] = e;
    }
    for (int n = 0; n < 36; n++) { a.ostart[n] = 0; a.ocnt[n] = 0; }
    for (int e = 0; e < 120; e++) {
        a.ocnt[a.src[e]]++;
        if (e == 0 || a.src[e] != a.src[e - 1]) a.ostart[a.src[e]] = e;
    }
    return a;
}

__device__ constexpr AdjT ADJC = build_adj();
__device__ constexpr int G16_START[17] =
    {0, 3, 6, 9, 12, 14, 16, 18, 20, 22, 24, 26, 28, 30, 32, 34, 36};

// ---------------------------------------------------------------------------
// K0a: composite conv1*conv2 weight prep (conv1 and conv2 compose LINEARLY —
// no activation between them). Wc[co][t], t in 9x9=81 taps (pad 96):
//   Wc[t] = sum_ci sum_{t1+t2=t} w1[ci][t1] * w2[co][ci][t2]
//   bc[co] = b2[co] + sum_ci b1[ci] * sum_t2 w2[co][ci][t2]
// Emitted directly as B-frags: wpc[3 ks][2 nt][64 lane][8 j], co=2n+nt,
// k = ks*32 + q*8 + j (zero for k>=81). grid 13*256 >= 3104.
// ---------------------------------------------------------------------------
__global__ __launch_bounds__(256) void k_prepc(
    const float* __restrict__ w1, const float* __restrict__ b1,
    const float* __restrict__ w2, const float* __restrict__ b2,
    unsigned short* __restrict__ wpc, float* __restrict__ wcb) {
    int e = blockIdx.x * 256 + threadIdx.x;
    if (e < 3072) {
        int j = e & 7, lane = (e >> 3) & 63, nt = (e >> 9) & 1, ks = e >> 10;
        int n = lane & 15, q = lane >> 4;
        int co = 2 * n + nt;
        int t = ks * 32 + q * 8 + j;
        float val = 0.f;
        if (t < 81) {
            int ty = t / 9, tx = t - 9 * ty;
            int ylo = ty > 4 ? ty - 4 : 0, yhi = ty < 4 ? ty : 4;
            int xlo = tx > 4 ? tx - 4 : 0, xhi = tx < 4 ? tx : 4;
            for (int ci = 0; ci < 32; ci++)
                for (int k1y = ylo; k1y <= yhi; k1y++)
                    for (int k1x = xlo; k1x <= xhi; k1x++)
                        val += w1[ci * 25 + k1y * 5 + k1x] *
                               w2[co * 800 + ci * 25 + (ty - k1y) * 5 + (tx - k1x)];
        }
        wpc[e] = f2bf(val);
    } else if (e < 3104) {
        int co = e - 3072;
        float s = b2[co];
        for (int ci = 0; ci < 32; ci++) {
            float ws = 0.f;
            for (int t2 = 0; t2 < 25; t2++) ws += w2[co * 800 + ci * 25 + t2];
            s += b1[ci] * ws;
        }
        wcb[co] = s;
    }
}

// ---------------------------------------------------------------------------
// K0b: prep for conv3/conv4 + heads (verified R9-R12 sections, reindexed).
// grid 1288*256 = 329728 = 51200 + 102400 + 176128 exactly.
// ---------------------------------------------------------------------------
__global__ __launch_bounds__(256) void k_prepall(
    const float* __restrict__ w3, const float* __restrict__ w4,
    const float* __restrict__ cnw1, const float* __restrict__ epw1,
    const float* __restrict__ cnw2, const float* __restrict__ epw2,
    unsigned short* __restrict__ wp3, unsigned short* __restrict__ wp4,
    unsigned short* __restrict__ wph1, unsigned short* __restrict__ wpcn2,
    unsigned short* __restrict__ wpep2) {
    int e = blockIdx.x * 256 + threadIdx.x;
    if (e < 51200) {
        int j = e & 7, lane = (e >> 3) & 63, nt = (e >> 9) & 3, t = e >> 11;
        int co = 4 * (lane & 15) + nt, ci = (lane >> 4) * 8 + j;
        wp3[e] = f2bf(w3[(co * 32 + ci) * 25 + t]);
    } else if (e < 153600) {
        int e4 = e - 51200;
        int j = e4 & 7, lane = (e4 >> 3) & 63, nt = (e4 >> 9) & 3;
        int ks = (e4 >> 11) & 1, t = e4 >> 12;
        int co = 4 * (lane & 15) + nt, ci = ks * 32 + (lane >> 4) * 8 + j;
        wp4[e4] = f2bf(w4[(co * 64 + ci) * 25 + t]);
    } else {
        int eh = e - 153600;
        if (eh < 131072) {
            int j = eh & 7, lane = (eh >> 3) & 63, nt = (eh >> 9) & 31, kt = eh >> 14;
            int c = nt * 16 + (lane & 15);
            int k = kt * 32 + ((lane >> 4) << 3) + j;
            float v = (c < 256) ? cnw1[c * 256 + k] : epw1[(c - 256) * 256 + k];
            wph1[eh] = f2bf(v);
        } else if (eh < 163840) {
            int e2 = eh - 131072;
            int j = e2 & 7, lane = (e2 >> 3) & 63, nt = (e2 >> 9) & 7, kt = e2 >> 12;
            int c = nt * 16 + (lane & 15);
            int k = kt * 32 + ((lane >> 4) << 3) + j;
            wpcn2[e2] = f2bf(c < 120 ? cnw2[c * 256 + k] : 0.f);
        } else {
            int e3 = eh - 163840;
            int j = e3 & 7, lane = (e3 >> 3) & 63, idx = e3 >> 9;
            int kt = idx / 3, nt = idx - kt * 3;
            int c = nt * 16 + (lane & 15);
            int k = kt * 32 + ((lane >> 4) << 3) + j;
            wpep2[e3] = f2bf(c < 36 ? epw2[c * 256 + k] : 0.f);
        }
    }
}

// ---------------------------------------------------------------------------
// K_CONVALL R13: composite 9x9 conv (conv1∘conv2, K=81 pad 96) with
// IN-REGISTER pooling, then conv3 + conv4 + pool + flatten. 512 thr/block.
// Mtile = 4 pooled outputs x (2x2 subpos): D rows quad*4..+3 are exactly one
// pool window per lane -> max in registers, write p2 directly. No conv1-out
// buffer, no conv2 staging, no pool phase. LDS ~23 KB -> 4 blocks/CU.
// s_buf regions (ushort idx): p2 [144][40] @ [0,5760); s_c3 [64][72] @
// [5760,10368); s_c4 f32 [16][68] @ [0,2176) (p2 dead after conv3).
// ---------------------------------------------------------------------------
__global__ __launch_bounds__(512) void k_convall(
    const float* __restrict__ img,
    const unsigned short* __restrict__ wpc, const float* __restrict__ wcb,
    const unsigned short* __restrict__ wp3, const float* __restrict__ b3,
    const unsigned short* __restrict__ wp4, const float* __restrict__ b4,
    unsigned short* __restrict__ emb) {
    __shared__ __align__(16) unsigned short s_imgbf[32 * 36];
    __shared__ __align__(16) unsigned short s_buf[10368];
    const int b = blockIdx.x, tid = threadIdx.x;
    const int lane = tid & 63, wave = tid >> 6;
    const int m = lane & 15, quad = lane >> 4;
    const int C3O = 5760;

    // stage full image as bf16 (first 256 threads)
    if (tid < 256) {
        float4 t = ((const float4*)(img + (size_t)b * 1024))[tid];
        ushort4v pkv;
        pkv[0] = f2bf(t.x); pkv[1] = f2bf(t.y);
        pkv[2] = f2bf(t.z); pkv[3] = f2bf(t.w);
        *(ushort4v*)(s_imgbf + (tid >> 3) * 36 + (tid & 7) * 4) = pkv;
    }

    // composite-conv B-frags (held in regs all phase) + bias + tap offsets
    const short8* wqc = (const short8*)wpc;
    short8 cb0[3], cb1[3];
#pragma unroll
    for (int ks = 0; ks < 3; ks++) {
        cb0[ks] = wqc[(ks * 2 + 0) * 64 + lane];
        cb1[ks] = wqc[(ks * 2 + 1) * 64 + lane];
    }
    const float bc0 = wcb[2 * m], bc1 = wcb[2 * m + 1];
    int ct[3][8];
#pragma unroll
    for (int ks = 0; ks < 3; ks++)
#pragma unroll
        for (int j = 0; j < 8; j++) {
            int t = ks * 32 + quad * 8 + j;
            int toff = 0;
            if (t < 81) {
                int ty = (t * 57) >> 9;   // == t/9 for t<90
                toff = ty * 36 + (t - 9 * ty);
            }
            ct[ks][j] = toff;            // taps >=81 read garbage * B=0 -> 0
        }
    // conv3 B-frag prefetch pointer
    const short8* wq3 = (const short8*)wp3;

    __syncthreads();

    // ---- composite conv + in-register pool -> p2 [144][40] ----
    for (int T = wave; T < 36; T += 8) {
        int pg = T * 4 + (m >> 2);            // pooled output index 0..143
        int py = (pg * 171) >> 11;            // == pg/12 for pg<144
        int px = pg - py * 12;
        int wb = (2 * py + ((m & 3) >> 1)) * 36 + 2 * px + (m & 1);
        float4v a0 = {0.f, 0.f, 0.f, 0.f};
        float4v a1 = {0.f, 0.f, 0.f, 0.f};
#pragma unroll
        for (int ks = 0; ks < 3; ks++) {
            short8 av;
#pragma unroll
            for (int j = 0; j < 8; j++) av[j] = (short)s_imgbf[wb + ct[ks][j]];
            a0 = __builtin_amdgcn_mfma_f32_16x16x32_bf16(av, cb0[ks], a0, 0, 0, 0);
            a1 = __builtin_amdgcn_mfma_f32_16x16x32_bf16(av, cb1[ks], a1, 0, 0, 0);
        }
        float mx0 = fmaxf(fmaxf(a0[0], a0[1]), fmaxf(a0[2], a0[3])) + bc0;
        float mx1 = fmaxf(fmaxf(a1[0], a1[1]), fmaxf(a1[2], a1[3])) + bc1;
        int row = T * 4 + quad;
        *(unsigned*)(s_buf + row * 40 + 2 * m) = pk2(mx0, mx1);
    }
    __syncthreads();

    // ---- conv3: Mtile = wave>>1 (pos3 in 8x8 grid), Ntile half = wave&1 ----
    {
        int pos3 = (wave >> 1) * 16 + m;
        int y3 = pos3 >> 3, x3 = pos3 & 7;
        int a3 = (y3 * 12 + x3) * 40 + quad * 8;
        int nt0 = (wave & 1) * 2;
        float4v acc3[2];
        acc3[0] = (float4v){0.f, 0.f, 0.f, 0.f};
        acc3[1] = (float4v){0.f, 0.f, 0.f, 0.f};
        short8 bw3[2];
        bw3[0] = wq3[nt0 * 64 + lane];
        bw3[1] = wq3[(nt0 + 1) * 64 + lane];
        for (int t = 0; t < 25; t++) {
            short8 nb3[2];
            if (t < 24) {
                nb3[0] = wq3[((t + 1) * 4 + nt0) * 64 + lane];
                nb3[1] = wq3[((t + 1) * 4 + nt0 + 1) * 64 + lane];
            }
            const int ky = t / 5, kx = t - ky * 5;
            short8 av = *(const short8*)(s_buf + a3 + (ky * 12 + kx) * 40);
            acc3[0] = __builtin_amdgcn_mfma_f32_16x16x32_bf16(av, bw3[0], acc3[0], 0, 0, 0);
            acc3[1] = __builtin_amdgcn_mfma_f32_16x16x32_bf16(av, bw3[1], acc3[1], 0, 0, 0);
            if (t < 24) { bw3[0] = nb3[0]; bw3[1] = nb3[1]; }
        }
        float bb0 = b3[4 * m + nt0], bb1 = b3[4 * m + nt0 + 1];
#pragma unroll
        for (int r = 0; r < 4; r++) {
            int row3 = (wave >> 1) * 16 + quad * 4 + r;
            *(unsigned*)(s_buf + C3O + row3 * 72 + 4 * m + nt0) =
                pk2(acc3[0][r] + bb0, acc3[1][r] + bb1);
        }
    }
    __syncthreads();

    // ---- conv4: waves 0-3 (Ntile = wave, 2 Ksteps); waves 4-7 idle ----
    if (wave < 4) {
        int y4 = m >> 2, x4 = m & 3;
        int a4 = C3O + (y4 * 8 + x4) * 72 + quad * 8;
        float4v acc4 = (float4v){0.f, 0.f, 0.f, 0.f};
        const short8* wq4 = (const short8*)wp4;
        short8 cw0 = wq4[(0 * 4 + wave) * 64 + lane];
        short8 cw1 = wq4[(1 * 4 + wave) * 64 + lane];
        for (int t = 0; t < 25; t++) {
            short8 n0, n1;
            if (t < 24) {
                n0 = wq4[(((t + 1) * 2) * 4 + wave) * 64 + lane];
                n1 = wq4[(((t + 1) * 2 + 1) * 4 + wave) * 64 + lane];
            }
            const int ky = t / 5, kx = t - ky * 5;
            const int toff = (ky * 8 + kx) * 72;
            short8 av0 = *(const short8*)(s_buf + a4 + toff);
            acc4 = __builtin_amdgcn_mfma_f32_16x16x32_bf16(av0, cw0, acc4, 0, 0, 0);
            short8 av1 = *(const short8*)(s_buf + a4 + toff + 32);
            acc4 = __builtin_amdgcn_mfma_f32_16x16x32_bf16(av1, cw1, acc4, 0, 0, 0);
            if (t < 24) { cw0 = n0; cw1 = n1; }
        }
        // s_c4 f32 [16][68] @ ushort [0,2176) — p2 dead, disjoint from s_c3
        float* s_c4 = (float*)s_buf;
#pragma unroll
        for (int r = 0; r < 4; r++)
            s_c4[(quad * 4 + r) * 68 + 4 * m + wave] = acc4[r];
    }
    __syncthreads();

    // emb epilogue: tid = co*4 + pp; pool 2x2 + bias4 + flatten
    if (tid < 256) {
        const float* s_c4 = (const float*)s_buf;
        int co = tid >> 2, pp = tid & 3;
        int ppy = pp >> 1, ppx = pp & 1;
        float v0 = s_c4[((2 * ppy) * 4 + 2 * ppx) * 68 + co];
        float v1 = s_c4[((2 * ppy) * 4 + 2 * ppx + 1) * 68 + co];
        float v2 = s_c4[((2 * ppy + 1) * 4 + 2 * ppx) * 68 + co];
        float v3 = s_c4[((2 * ppy + 1) * 4 + 2 * ppx + 1) * 68 + co];
        emb[(size_t)b * 256 + tid] =
            f2bf(fmaxf(fmaxf(v0, v1), fmaxf(v2, v3)) + b4[co]);
    }
}

// ---------------------------------------------------------------------------
// K5: fused heads (MFMA) + DAMP recurrence (verified R4-R12, unchanged).
// ---------------------------------------------------------------------------
__global__ __launch_bounds__(256) void k_heads(
    const unsigned short* __restrict__ emb,
    const unsigned short* __restrict__ wph1,
    const float* __restrict__ cn_b1, const float* __restrict__ ep_b1,
    const unsigned short* __restrict__ wpcn2, const float* __restrict__ cn_b2,
    const unsigned short* __restrict__ wpep2, const float* __restrict__ ep_b2,
    float* __restrict__ out) {
    __shared__ unsigned short s_hid[16 * 520];
    __shared__ float s_conn[120 * 17];
    __shared__ float s_rec0[120 * 17];
    __shared__ float s_rec1[120 * 17];
    __shared__ float s_ep[36 * 17];
    const int tid = threadIdx.x;
    const int lane = tid & 63, wave = tid >> 6;
    const int m = lane & 15, q = lane >> 4;
    const int b0 = blockIdx.x * 16;

    float4v acc[8];
#pragma unroll
    for (int i = 0; i < 8; i++) acc[i] = (float4v){0.f, 0.f, 0.f, 0.f};
    const short8* wp1 = (const short8*)wph1;
    for (int kt = 0; kt < 8; kt++) {
        short8 av = *(const short8*)(emb + (size_t)(b0 + m) * 256 + kt * 32 + q * 8);
#pragma unroll
        for (int ntl = 0; ntl < 8; ntl++) {
            int nt = wave * 8 + ntl;
            short8 bv = wp1[(kt * 32 + nt) * 64 + lane];
            acc[ntl] = __builtin_amdgcn_mfma_f32_16x16x32_bf16(av, bv, acc[ntl], 0, 0, 0);
        }
    }
#pragma unroll
    for (int ntl = 0; ntl < 8; ntl++) {
        int c = (wave * 8 + ntl) * 16 + m;
        float bb = (c < 256) ? cn_b1[c] : ep_b1[c - 256];
#pragma unroll
        for (int r = 0; r < 4; r++)
            s_hid[(q * 4 + r) * 520 + c] = f2bf(fmaxf(acc[ntl][r] + bb, 0.f));
    }
    __syncthreads();

    for (int job = wave; job < 11; job += 4) {
        const bool isconn = job < 8;
        const int koff = isconn ? 0 : 256;
        float4v a2 = (float4v){0.f, 0.f, 0.f, 0.f};
        for (int kt = 0; kt < 8; kt++) {
            short8 av = *(const short8*)(s_hid + m * 520 + koff + kt * 32 + q * 8);
            short8 bv = isconn
                ? ((const short8*)wpcn2)[(kt * 8 + job) * 64 + lane]
                : ((const short8*)wpep2)[(kt * 3 + (job - 8)) * 64 + lane];
            a2 = __builtin_amdgcn_mfma_f32_16x16x32_bf16(av, bv, a2, 0, 0, 0);
        }
        int c = (isconn ? job : (job - 8)) * 16 + m;
        float bb = isconn ? (c < 120 ? cn_b2[c] : 0.f) : (c < 36 ? ep_b2[c] : 0.f);
#pragma unroll
        for (int r = 0; r < 4; r++) {
            float v = 1.f / (1.f + __expf(-(a2[r] + bb)));
            int row = q * 4 + r;
            if (isconn) {
                if (c < 120) { s_conn[c * 17 + row] = v; s_rec0[c * 17 + row] = v; }
            } else {
                if (c < 36) s_ep[c * 17 + row] = v;
            }
        }
    }
    __syncthreads();

    const int row = tid >> 4, g = tid & 15;
    const int ns = G16_START[g];
    const int nodecnt = G16_START[g + 1] - ns;
    int ie[3][4], icnt[3], os[3], oc[3];
    float cr[3][4];
#pragma unroll
    for (int s = 0; s < 3; s++) {
        if (s < nodecnt) {
            int n = ns + s;
            icnt[s] = ADJC.cnt[n];
#pragma unroll
            for (int qx = 0; qx < 4; qx++) ie[s][qx] = ADJC.idx[n][qx];
            os[s] = ADJC.ostart[n];
            oc[s] = ADJC.ocnt[n];
#pragma unroll
            for (int oe = 0; oe < 4; oe++)
                cr[s][oe] = (oe < oc[s]) ? s_conn[(os[s] + oe) * 17 + row] : 0.f;
        } else {
            icnt[s] = 0; oc[s] = 0; os[s] = 0;
#pragma unroll
            for (int qx = 0; qx < 4; qx++) ie[s][qx] = 0;
#pragma unroll
            for (int oe = 0; oe < 4; oe++) cr[s][oe] = 0.f;
        }
    }
    float old0 = (g == 0) ? s_conn[0 * 17 + row] : 0.f;

    for (int it = 0; it < 36; it++) {
        const float* cur = (it & 1) ? s_rec1 : s_rec0;
        float* nxt = (it & 1) ? s_rec0 : s_rec1;
#pragma unroll
        for (int s = 0; s < 3; s++) {
            float sum = 0.f;
#pragma unroll
            for (int qx = 0; qx < 4; qx++)
                sum += (qx < icnt[s]) ? cur[ie[s][qx] * 17 + row] : 0.f;
            sum = fminf(sum, 1.f);
#pragma unroll
            for (int oe = 0; oe < 4; oe++) {
                if (oe < oc[s]) {
                    int e = os[s] + oe;
                    float nv = sum * cr[s][oe];
                    nxt[e * 17 + row] = nv;
                    if (g == 0 && s == 0 && oe == 0)
                        old0 = fminf(old0 + nv, 1.f);
                }
            }
        }
        __asm__ volatile("s_waitcnt lgkmcnt(0)" ::: "memory");
    }

    if (g == 0)
        out[b0 + row] = old0 * s_ep[0 * 17 + row] * s_ep[6 * 17 + row];
}

// ---------------------------------------------------------------------------
extern "C" void kernel_launch(void* const* d_in, const int* in_sizes, int n_in,
                              void* d_out, int out_size, void* d_ws, size_t ws_size,
                              hipStream_t stream) {
    const float* image = (const float*)d_in[0];
    const float* c1w = (const float*)d_in[1];
    const float* c1b = (const float*)d_in[2];
    const float* c2w = (const float*)d_in[3];
    const float* c2b = (const float*)d_in[4];
    const float* c3w = (const float*)d_in[5];
    const float* c3b = (const float*)d_in[6];
    const float* c4w = (const float*)d_in[7];
    const float* c4b = (const float*)d_in[8];
    const float* epw1 = (const float*)d_in[9];
    const float* epb1 = (const float*)d_in[10];
    const float* epw2 = (const float*)d_in[11];
    const float* epb2 = (const float*)d_in[12];
    const float* cnw1 = (const float*)d_in[13];
    const float* cnb1 = (const float*)d_in[14];
    const float* cnw2 = (const float*)d_in[15];
    const float* cnb2 = (const float*)d_in[16];

    const int B = in_sizes[0] / (32 * 32);  // 1024

    unsigned short* ws = (unsigned short*)d_ws;
    unsigned short* embo = ws;                            // B*256 bf16
    unsigned short* wp3 = embo + (size_t)B * 256;         // 51200
    unsigned short* wp4 = wp3 + 51200;                    // 102400
    unsigned short* wph1 = wp4 + 102400;                  // 131072
    unsigned short* wpcn2 = wph1 + 131072;                // 32768
    unsigned short* wpep2 = wpcn2 + 32768;                // 12288
    unsigned short* wpc = wpep2 + 12288;                  // 3072
    float* wcb = (float*)(wpc + 3072);                    // 32 f32

    k_prepc<<<13, 256, 0, stream>>>(c1w, c1b, c2w, c2b, wpc, wcb);
    k_prepall<<<1288, 256, 0, stream>>>(c3w, c4w, cnw1, epw1, cnw2, epw2,
                                        wp3, wp4, wph1, wpcn2, wpep2);
    k_convall<<<B, 512, 0, stream>>>(image, wpc, wcb, wp3, c3b, wp4, c4b, embo);
    k_heads<<<B / 16, 256, 0, stream>>>(embo, wph1, cnb1, epb1,
                                        wpcn2, cnb2, wpep2, epb2, (float*)d_out);
}

// Round 14
// 191.693 us; speedup vs baseline: 1.1892x; 1.1892x over previous
//
#include <hip/hip_runtime.h>
#include <math.h>

typedef __attribute__((ext_vector_type(8))) short short8;
typedef __attribute__((ext_vector_type(4))) float float4v;
typedef __attribute__((ext_vector_type(4))) unsigned short ushort4v;

static __device__ __forceinline__ unsigned short f2bf(float f) {
    union { float f; unsigned u; } v; v.f = f;
    unsigned u = v.u;
    return (unsigned short)((u + 0x7fffu + ((u >> 16) & 1u)) >> 16);
}
static __device__ __forceinline__ float bf2f(unsigned short h) {
    union { unsigned u; float f; } v; v.u = ((unsigned)h) << 16;
    return v.f;
}
static __device__ __forceinline__ unsigned pk2(float a, float b) {
    return (unsigned)f2bf(a) | ((unsigned)f2bf(b) << 16);
}

// ---------------------------------------------------------------------------
// Graph structure (compile-time), matching Python enumeration order.
// ---------------------------------------------------------------------------
struct AdjT {
    int src[120];
    int dst[120];
    int cnt[36];
    int idx[36][4];
    int ostart[36];
    int ocnt[36];
};

constexpr AdjT build_adj() {
    AdjT a{};
    const int ddx[4] = {-1, 0, 0, 1};
    const int ddy[4] = {0, -1, 1, 0};
    int ne = 0;
    for (int i = 0; i < 6; i++)
        for (int j = 0; j < 6; j++)
            for (int d = 0; d < 4; d++) {
                int x = i + ddx[d], y = j + ddy[d];
                if (x >= 0 && x < 6 && y >= 0 && y < 6) {
                    a.src[ne] = j * 6 + i;
                    a.dst[ne] = y * 6 + x;
                    ne++;
                }
            }
    for (int n = 0; n < 36; n++) {
        a.cnt[n] = 0;
        for (int e = 0; e < 120; e++)
            if (a.dst[e] == n) a.idx[n][a.cnt[n]++] = e;
    }
    for (int n = 0; n < 36; n++) { a.ostart[n] = 0; a.ocnt[n] = 0; }
    for (int e = 0; e < 120; e++) {
        a.ocnt[a.src[e]]++;
        if (e == 0 || a.src[e] != a.src[e - 1]) a.ostart[a.src[e]] = e;
    }
    return a;
}

__device__ constexpr AdjT ADJC = build_adj();
__device__ constexpr int G16_START[17] =
    {0, 3, 6, 9, 12, 14, 16, 18, 20, 22, 24, 26, 28, 30, 32, 34, 36};

// ---------------------------------------------------------------------------
// K0: merged prep. Blocks 0..31: composite conv1∘conv2 weights (one block per
// co, w1+w2[co] staged to LDS -> taps computed from LDS; fixes R13's 78 us
// latency-bound k_prepc at 13 blocks / 800-deep global-load chains).
// Blocks 32..1319: elementwise B-frag prep for conv3/conv4 + heads.
//   Wc[co][t] = sum_ci sum_{t1+t2=t} w1[ci][t1]*w2[co][ci][t2]   (t in 9x9)
//   bc[co]    = b2[co] + sum_ci b1[ci]*sum_t2 w2[co][ci][t2]
// wpc B-frag layout: [3 ks][2 nt][64 lane][8 j], co=2n+nt, k=ks*32+q*8+j.
// ---------------------------------------------------------------------------
__global__ __launch_bounds__(256) void k_prepall(
    const float* __restrict__ w1, const float* __restrict__ b1,
    const float* __restrict__ w2, const float* __restrict__ b2,
    const float* __restrict__ w3, const float* __restrict__ w4,
    const float* __restrict__ cnw1, const float* __restrict__ epw1,
    const float* __restrict__ cnw2, const float* __restrict__ epw2,
    unsigned short* __restrict__ wpc, float* __restrict__ wcb,
    unsigned short* __restrict__ wp3, unsigned short* __restrict__ wp4,
    unsigned short* __restrict__ wph1, unsigned short* __restrict__ wpcn2,
    unsigned short* __restrict__ wpep2) {
    __shared__ float s_w1[800];
    __shared__ float s_w2[800];
    if (blockIdx.x < 32) {
        const int co = blockIdx.x, tid = threadIdx.x;
        for (int i = tid; i < 800; i += 256) {
            s_w1[i] = w1[i];
            s_w2[i] = w2[co * 800 + i];
        }
        __syncthreads();
        if (tid < 96) {
            int t = tid;
            float val = 0.f;
            if (t < 81) {
                int ty = t / 9, tx = t - 9 * ty;
                int ylo = ty > 4 ? ty - 4 : 0, yhi = ty < 4 ? ty : 4;
                int xlo = tx > 4 ? tx - 4 : 0, xhi = tx < 4 ? tx : 4;
                for (int ci = 0; ci < 32; ci++)
                    for (int k1y = ylo; k1y <= yhi; k1y++)
                        for (int k1x = xlo; k1x <= xhi; k1x++)
                            val += s_w1[ci * 25 + k1y * 5 + k1x] *
                                   s_w2[ci * 25 + (ty - k1y) * 5 + (tx - k1x)];
            }
            int n = co >> 1, nt = co & 1;
            int ks = t >> 5, r = t & 31, q = r >> 3, j = r & 7;
            wpc[ks * 1024 + nt * 512 + (q * 16 + n) * 8 + j] = f2bf(val);
        } else if (tid == 96) {
            float s = b2[co];
            for (int ci = 0; ci < 32; ci++) {
                float ws = 0.f;
                for (int t2 = 0; t2 < 25; t2++) ws += s_w2[ci * 25 + t2];
                s += b1[ci] * ws;
            }
            wcb[co] = s;
        }
        return;
    }
    int e = (blockIdx.x - 32) * 256 + threadIdx.x;
    if (e < 51200) {
        int j = e & 7, lane = (e >> 3) & 63, nt = (e >> 9) & 3, t = e >> 11;
        int co = 4 * (lane & 15) + nt, ci = (lane >> 4) * 8 + j;
        wp3[e] = f2bf(w3[(co * 32 + ci) * 25 + t]);
    } else if (e < 153600) {
        int e4 = e - 51200;
        int j = e4 & 7, lane = (e4 >> 3) & 63, nt = (e4 >> 9) & 3;
        int ks = (e4 >> 11) & 1, t = e4 >> 12;
        int co = 4 * (lane & 15) + nt, ci = ks * 32 + (lane >> 4) * 8 + j;
        wp4[e4] = f2bf(w4[(co * 64 + ci) * 25 + t]);
    } else {
        int eh = e - 153600;
        if (eh < 131072) {
            int j = eh & 7, lane = (eh >> 3) & 63, nt = (eh >> 9) & 31, kt = eh >> 14;
            int c = nt * 16 + (lane & 15);
            int k = kt * 32 + ((lane >> 4) << 3) + j;
            float v = (c < 256) ? cnw1[c * 256 + k] : epw1[(c - 256) * 256 + k];
            wph1[eh] = f2bf(v);
        } else if (eh < 163840) {
            int e2 = eh - 131072;
            int j = e2 & 7, lane = (e2 >> 3) & 63, nt = (e2 >> 9) & 7, kt = e2 >> 12;
            int c = nt * 16 + (lane & 15);
            int k = kt * 32 + ((lane >> 4) << 3) + j;
            wpcn2[e2] = f2bf(c < 120 ? cnw2[c * 256 + k] : 0.f);
        } else {
            int e3 = eh - 163840;
            int j = e3 & 7, lane = (e3 >> 3) & 63, idx = e3 >> 9;
            int kt = idx / 3, nt = idx - kt * 3;
            int c = nt * 16 + (lane & 15);
            int k = kt * 32 + ((lane >> 4) << 3) + j;
            wpep2[e3] = f2bf(c < 36 ? epw2[c * 256 + k] : 0.f);
        }
    }
}

// ---------------------------------------------------------------------------
// K_CONVALL: composite 9x9 conv (conv1∘conv2, K=81 pad 96) with in-register
// pooling, then conv3 + conv4 + pool + flatten (verified R13). 512 thr/block.
// s_buf regions (ushort idx): p2 [144][40] @ [0,5760); s_c3 [64][72] @
// [5760,10368); s_c4 f32 [16][68] @ [0,2176) (p2 dead after conv3).
// ---------------------------------------------------------------------------
__global__ __launch_bounds__(512) void k_convall(
    const float* __restrict__ img,
    const unsigned short* __restrict__ wpc, const float* __restrict__ wcb,
    const unsigned short* __restrict__ wp3, const float* __restrict__ b3,
    const unsigned short* __restrict__ wp4, const float* __restrict__ b4,
    unsigned short* __restrict__ emb) {
    __shared__ __align__(16) unsigned short s_imgbf[32 * 36];
    __shared__ __align__(16) unsigned short s_buf[10368];
    const int b = blockIdx.x, tid = threadIdx.x;
    const int lane = tid & 63, wave = tid >> 6;
    const int m = lane & 15, quad = lane >> 4;
    const int C3O = 5760;

    // stage full image as bf16 (first 256 threads)
    if (tid < 256) {
        float4 t = ((const float4*)(img + (size_t)b * 1024))[tid];
        ushort4v pkv;
        pkv[0] = f2bf(t.x); pkv[1] = f2bf(t.y);
        pkv[2] = f2bf(t.z); pkv[3] = f2bf(t.w);
        *(ushort4v*)(s_imgbf + (tid >> 3) * 36 + (tid & 7) * 4) = pkv;
    }

    // composite-conv B-frags (held in regs all phase) + bias + tap offsets
    const short8* wqc = (const short8*)wpc;
    short8 cb0[3], cb1[3];
#pragma unroll
    for (int ks = 0; ks < 3; ks++) {
        cb0[ks] = wqc[(ks * 2 + 0) * 64 + lane];
        cb1[ks] = wqc[(ks * 2 + 1) * 64 + lane];
    }
    const float bc0 = wcb[2 * m], bc1 = wcb[2 * m + 1];
    int ct[3][8];
#pragma unroll
    for (int ks = 0; ks < 3; ks++)
#pragma unroll
        for (int j = 0; j < 8; j++) {
            int t = ks * 32 + quad * 8 + j;
            int toff = 0;
            if (t < 81) {
                int ty = (t * 57) >> 9;   // == t/9 for t<90
                toff = ty * 36 + (t - 9 * ty);
            }
            ct[ks][j] = toff;            // taps >=81 read garbage * B=0 -> 0
        }
    const short8* wq3 = (const short8*)wp3;

    __syncthreads();

    // ---- composite conv + in-register pool -> p2 [144][40] ----
    for (int T = wave; T < 36; T += 8) {
        int pg = T * 4 + (m >> 2);            // pooled output index 0..143
        int py = (pg * 171) >> 11;            // == pg/12 for pg<144
        int px = pg - py * 12;
        int wb = (2 * py + ((m & 3) >> 1)) * 36 + 2 * px + (m & 1);
        float4v a0 = {0.f, 0.f, 0.f, 0.f};
        float4v a1 = {0.f, 0.f, 0.f, 0.f};
#pragma unroll
        for (int ks = 0; ks < 3; ks++) {
            short8 av;
#pragma unroll
            for (int j = 0; j < 8; j++) av[j] = (short)s_imgbf[wb + ct[ks][j]];
            a0 = __builtin_amdgcn_mfma_f32_16x16x32_bf16(av, cb0[ks], a0, 0, 0, 0);
            a1 = __builtin_amdgcn_mfma_f32_16x16x32_bf16(av, cb1[ks], a1, 0, 0, 0);
        }
        float mx0 = fmaxf(fmaxf(a0[0], a0[1]), fmaxf(a0[2], a0[3])) + bc0;
        float mx1 = fmaxf(fmaxf(a1[0], a1[1]), fmaxf(a1[2], a1[3])) + bc1;
        int row = T * 4 + quad;
        *(unsigned*)(s_buf + row * 40 + 2 * m) = pk2(mx0, mx1);
    }
    __syncthreads();

    // ---- conv3: Mtile = wave>>1 (pos3 in 8x8 grid), Ntile half = wave&1 ----
    {
        int pos3 = (wave >> 1) * 16 + m;
        int y3 = pos3 >> 3, x3 = pos3 & 7;
        int a3 = (y3 * 12 + x3) * 40 + quad * 8;
        int nt0 = (wave & 1) * 2;
        float4v acc3[2];
        acc3[0] = (float4v){0.f, 0.f, 0.f, 0.f};
        acc3[1] = (float4v){0.f, 0.f, 0.f, 0.f};
        short8 bw3[2];
        bw3[0] = wq3[nt0 * 64 + lane];
        bw3[1] = wq3[(nt0 + 1) * 64 + lane];
        for (int t = 0; t < 25; t++) {
            short8 nb3[2];
            if (t < 24) {
                nb3[0] = wq3[((t + 1) * 4 + nt0) * 64 + lane];
                nb3[1] = wq3[((t + 1) * 4 + nt0 + 1) * 64 + lane];
            }
            const int ky = t / 5, kx = t - ky * 5;
            short8 av = *(const short8*)(s_buf + a3 + (ky * 12 + kx) * 40);
            acc3[0] = __builtin_amdgcn_mfma_f32_16x16x32_bf16(av, bw3[0], acc3[0], 0, 0, 0);
            acc3[1] = __builtin_amdgcn_mfma_f32_16x16x32_bf16(av, bw3[1], acc3[1], 0, 0, 0);
            if (t < 24) { bw3[0] = nb3[0]; bw3[1] = nb3[1]; }
        }
        float bb0 = b3[4 * m + nt0], bb1 = b3[4 * m + nt0 + 1];
#pragma unroll
        for (int r = 0; r < 4; r++) {
            int row3 = (wave >> 1) * 16 + quad * 4 + r;
            *(unsigned*)(s_buf + C3O + row3 * 72 + 4 * m + nt0) =
                pk2(acc3[0][r] + bb0, acc3[1][r] + bb1);
        }
    }
    __syncthreads();

    // ---- conv4: waves 0-3 (Ntile = wave, 2 Ksteps); waves 4-7 idle ----
    if (wave < 4) {
        int y4 = m >> 2, x4 = m & 3;
        int a4 = C3O + (y4 * 8 + x4) * 72 + quad * 8;
        float4v acc4 = (float4v){0.f, 0.f, 0.f, 0.f};
        const short8* wq4 = (const short8*)wp4;
        short8 cw0 = wq4[(0 * 4 + wave) * 64 + lane];
        short8 cw1 = wq4[(1 * 4 + wave) * 64 + lane];
        for (int t = 0; t < 25; t++) {
            short8 n0, n1;
            if (t < 24) {
                n0 = wq4[(((t + 1) * 2) * 4 + wave) * 64 + lane];
                n1 = wq4[(((t + 1) * 2 + 1) * 4 + wave) * 64 + lane];
            }
            const int ky = t / 5, kx = t - ky * 5;
            const int toff = (ky * 8 + kx) * 72;
            short8 av0 = *(const short8*)(s_buf + a4 + toff);
            acc4 = __builtin_amdgcn_mfma_f32_16x16x32_bf16(av0, cw0, acc4, 0, 0, 0);
            short8 av1 = *(const short8*)(s_buf + a4 + toff + 32);
            acc4 = __builtin_amdgcn_mfma_f32_16x16x32_bf16(av1, cw1, acc4, 0, 0, 0);
            if (t < 24) { cw0 = n0; cw1 = n1; }
        }
        float* s_c4 = (float*)s_buf;
#pragma unroll
        for (int r = 0; r < 4; r++)
            s_c4[(quad * 4 + r) * 68 + 4 * m + wave] = acc4[r];
    }
    __syncthreads();

    // emb epilogue: tid = co*4 + pp; pool 2x2 + bias4 + flatten
    if (tid < 256) {
        const float* s_c4 = (const float*)s_buf;
        int co = tid >> 2, pp = tid & 3;
        int ppy = pp >> 1, ppx = pp & 1;
        float v0 = s_c4[((2 * ppy) * 4 + 2 * ppx) * 68 + co];
        float v1 = s_c4[((2 * ppy) * 4 + 2 * ppx + 1) * 68 + co];
        float v2 = s_c4[((2 * ppy + 1) * 4 + 2 * ppx) * 68 + co];
        float v3 = s_c4[((2 * ppy + 1) * 4 + 2 * ppx + 1) * 68 + co];
        emb[(size_t)b * 256 + tid] =
            f2bf(fmaxf(fmaxf(v0, v1), fmaxf(v2, v3)) + b4[co]);
    }
}

// ---------------------------------------------------------------------------
// K5: fused heads (MFMA) + DAMP recurrence (verified R4-R13, unchanged).
// ---------------------------------------------------------------------------
__global__ __launch_bounds__(256) void k_heads(
    const unsigned short* __restrict__ emb,
    const unsigned short* __restrict__ wph1,
    const float* __restrict__ cn_b1, const float* __restrict__ ep_b1,
    const unsigned short* __restrict__ wpcn2, const float* __restrict__ cn_b2,
    const unsigned short* __restrict__ wpep2, const float* __restrict__ ep_b2,
    float* __restrict__ out) {
    __shared__ unsigned short s_hid[16 * 520];
    __shared__ float s_conn[120 * 17];
    __shared__ float s_rec0[120 * 17];
    __shared__ float s_rec1[120 * 17];
    __shared__ float s_ep[36 * 17];
    const int tid = threadIdx.x;
    const int lane = tid & 63, wave = tid >> 6;
    const int m = lane & 15, q = lane >> 4;
    const int b0 = blockIdx.x * 16;

    float4v acc[8];
#pragma unroll
    for (int i = 0; i < 8; i++) acc[i] = (float4v){0.f, 0.f, 0.f, 0.f};
    const short8* wp1 = (const short8*)wph1;
    for (int kt = 0; kt < 8; kt++) {
        short8 av = *(const short8*)(emb + (size_t)(b0 + m) * 256 + kt * 32 + q * 8);
#pragma unroll
        for (int ntl = 0; ntl < 8; ntl++) {
            int nt = wave * 8 + ntl;
            short8 bv = wp1[(kt * 32 + nt) * 64 + lane];
            acc[ntl] = __builtin_amdgcn_mfma_f32_16x16x32_bf16(av, bv, acc[ntl], 0, 0, 0);
        }
    }
#pragma unroll
    for (int ntl = 0; ntl < 8; ntl++) {
        int c = (wave * 8 + ntl) * 16 + m;
        float bb = (c < 256) ? cn_b1[c] : ep_b1[c - 256];
#pragma unroll
        for (int r = 0; r < 4; r++)
            s_hid[(q * 4 + r) * 520 + c] = f2bf(fmaxf(acc[ntl][r] + bb, 0.f));
    }
    __syncthreads();

    for (int job = wave; job < 11; job += 4) {
        const bool isconn = job < 8;
        const int koff = isconn ? 0 : 256;
        float4v a2 = (float4v){0.f, 0.f, 0.f, 0.f};
        for (int kt = 0; kt < 8; kt++) {
            short8 av = *(const short8*)(s_hid + m * 520 + koff + kt * 32 + q * 8);
            short8 bv = isconn
                ? ((const short8*)wpcn2)[(kt * 8 + job) * 64 + lane]
                : ((const short8*)wpep2)[(kt * 3 + (job - 8)) * 64 + lane];
            a2 = __builtin_amdgcn_mfma_f32_16x16x32_bf16(av, bv, a2, 0, 0, 0);
        }
        int c = (isconn ? job : (job - 8)) * 16 + m;
        float bb = isconn ? (c < 120 ? cn_b2[c] : 0.f) : (c < 36 ? ep_b2[c] : 0.f);
#pragma unroll
        for (int r = 0; r < 4; r++) {
            float v = 1.f / (1.f + __expf(-(a2[r] + bb)));
            int row = q * 4 + r;
            if (isconn) {
                if (c < 120) { s_conn[c * 17 + row] = v; s_rec0[c * 17 + row] = v; }
            } else {
                if (c < 36) s_ep[c * 17 + row] = v;
            }
        }
    }
    __syncthreads();

    const int row = tid >> 4, g = tid & 15;
    const int ns = G16_START[g];
    const int nodecnt = G16_START[g + 1] - ns;
    int ie[3][4], icnt[3], os[3], oc[3];
    float cr[3][4];
#pragma unroll
    for (int s = 0; s < 3; s++) {
        if (s < nodecnt) {
            int n = ns + s;
            icnt[s] = ADJC.cnt[n];
#pragma unroll
            for (int qx = 0; qx < 4; qx++) ie[s][qx] = ADJC.idx[n][qx];
            os[s] = ADJC.ostart[n];
            oc[s] = ADJC.ocnt[n];
#pragma unroll
            for (int oe = 0; oe < 4; oe++)
                cr[s][oe] = (oe < oc[s]) ? s_conn[(os[s] + oe) * 17 + row] : 0.f;
        } else {
            icnt[s] = 0; oc[s] = 0; os[s] = 0;
#pragma unroll
            for (int qx = 0; qx < 4; qx++) ie[s][qx] = 0;
#pragma unroll
            for (int oe = 0; oe < 4; oe++) cr[s][oe] = 0.f;
        }
    }
    float old0 = (g == 0) ? s_conn[0 * 17 + row] : 0.f;

    for (int it = 0; it < 36; it++) {
        const float* cur = (it & 1) ? s_rec1 : s_rec0;
        float* nxt = (it & 1) ? s_rec0 : s_rec1;
#pragma unroll
        for (int s = 0; s < 3; s++) {
            float sum = 0.f;
#pragma unroll
            for (int qx = 0; qx < 4; qx++)
                sum += (qx < icnt[s]) ? cur[ie[s][qx] * 17 + row] : 0.f;
            sum = fminf(sum, 1.f);
#pragma unroll
            for (int oe = 0; oe < 4; oe++) {
                if (oe < oc[s]) {
                    int e = os[s] + oe;
                    float nv = sum * cr[s][oe];
                    nxt[e * 17 + row] = nv;
                    if (g == 0 && s == 0 && oe == 0)
                        old0 = fminf(old0 + nv, 1.f);
                }
            }
        }
        __asm__ volatile("s_waitcnt lgkmcnt(0)" ::: "memory");
    }

    if (g == 0)
        out[b0 + row] = old0 * s_ep[0 * 17 + row] * s_ep[6 * 17 + row];
}

// ---------------------------------------------------------------------------
extern "C" void kernel_launch(void* const* d_in, const int* in_sizes, int n_in,
                              void* d_out, int out_size, void* d_ws, size_t ws_size,
                              hipStream_t stream) {
    const float* image = (const float*)d_in[0];
    const float* c1w = (const float*)d_in[1];
    const float* c1b = (const float*)d_in[2];
    const float* c2w = (const float*)d_in[3];
    const float* c2b = (const float*)d_in[4];
    const float* c3w = (const float*)d_in[5];
    const float* c3b = (const float*)d_in[6];
    const float* c4w = (const float*)d_in[7];
    const float* c4b = (const float*)d_in[8];
    const float* epw1 = (const float*)d_in[9];
    const float* epb1 = (const float*)d_in[10];
    const float* epw2 = (const float*)d_in[11];
    const float* epb2 = (const float*)d_in[12];
    const float* cnw1 = (const float*)d_in[13];
    const float* cnb1 = (const float*)d_in[14];
    const float* cnw2 = (const float*)d_in[15];
    const float* cnb2 = (const float*)d_in[16];

    const int B = in_sizes[0] / (32 * 32);  // 1024

    unsigned short* ws = (unsigned short*)d_ws;
    unsigned short* embo = ws;                            // B*256 bf16
    unsigned short* wp3 = embo + (size_t)B * 256;         // 51200
    unsigned short* wp4 = wp3 + 51200;                    // 102400
    unsigned short* wph1 = wp4 + 102400;                  // 131072
    unsigned short* wpcn2 = wph1 + 131072;                // 32768
    unsigned short* wpep2 = wpcn2 + 32768;                // 12288
    unsigned short* wpc = wpep2 + 12288;                  // 3072
    float* wcb = (float*)(wpc + 3072);                    // 32 f32

    k_prepall<<<1320, 256, 0, stream>>>(c1w, c1b, c2w, c2b, c3w, c4w,
                                        cnw1, epw1, cnw2, epw2,
                                        wpc, wcb, wp3, wp4, wph1, wpcn2, wpep2);
    k_convall<<<B, 512, 0, stream>>>(image, wpc, wcb, wp3, c3b, wp4, c4b, embo);
    k_heads<<<B / 16, 256, 0, stream>>>(embo, wph1, cnb1, epb1,
                                        wpcn2, cnb2, wpep2, epb2, (float*)d_out);
}

// Round 15
// 168.058 us; speedup vs baseline: 1.3564x; 1.1406x over previous
//
#include <hip/hip_runtime.h>
#include <math.h>

typedef __attribute__((ext_vector_type(8))) short short8;
typedef __attribute__((ext_vector_type(4))) float float4v;
typedef __attribute__((ext_vector_type(4))) unsigned short ushort4v;

static __device__ __forceinline__ unsigned short f2bf(float f) {
    union { float f; unsigned u; } v; v.f = f;
    unsigned u = v.u;
    return (unsigned short)((u + 0x7fffu + ((u >> 16) & 1u)) >> 16);
}
static __device__ __forceinline__ float bf2f(unsigned short h) {
    union { unsigned u; float f; } v; v.u = ((unsigned)h) << 16;
    return v.f;
}
static __device__ __forceinline__ unsigned pk2(float a, float b) {
    return (unsigned)f2bf(a) | ((unsigned)f2bf(b) << 16);
}

// ---------------------------------------------------------------------------
// Graph structure (compile-time), matching Python enumeration order.
// ---------------------------------------------------------------------------
struct AdjT {
    int src[120];
    int dst[120];
    int cnt[36];
    int idx[36][4];
    int ostart[36];
    int ocnt[36];
};

constexpr AdjT build_adj() {
    AdjT a{};
    const int ddx[4] = {-1, 0, 0, 1};
    const int ddy[4] = {0, -1, 1, 0};
    int ne = 0;
    for (int i = 0; i < 6; i++)
        for (int j = 0; j < 6; j++)
            for (int d = 0; d < 4; d++) {
                int x = i + ddx[d], y = j + ddy[d];
                if (x >= 0 && x < 6 && y >= 0 && y < 6) {
                    a.src[ne] = j * 6 + i;
                    a.dst[ne] = y * 6 + x;
                    ne++;
                }
            }
    for (int n = 0; n < 36; n++) {
        a.cnt[n] = 0;
        for (int e = 0; e < 120; e++)
            if (a.dst[e] == n) a.idx[n][a.cnt[n]++] = e;
    }
    for (int n = 0; n < 36; n++) { a.ostart[n] = 0; a.ocnt[n] = 0; }
    for (int e = 0; e < 120; e++) {
        a.ocnt[a.src[e]]++;
        if (e == 0 || a.src[e] != a.src[e - 1]) a.ostart[a.src[e]] = e;
    }
    return a;
}

__device__ constexpr AdjT ADJC = build_adj();
__device__ constexpr int G16_START[17] =
    {0, 3, 6, 9, 12, 14, 16, 18, 20, 22, 24, 26, 28, 30, 32, 34, 36};

// ---------------------------------------------------------------------------
// K0: merged prep. Blocks 0..31: composite conv1∘conv2 weights (one block per
// co). R15: ci loop innermost + fully unrolled — 64 independent ds_reads in
// flight per tap-offset iteration (R14 had runtime-bounded non-unrolled loops
// -> one dependent lgkmcnt(0) wait per iteration -> ~120 cyc x 800 = 40 us
// latency chain; now throughput-bound ~2-4 us).
// Blocks 32..1319: elementwise B-frag prep for conv3/conv4 + heads.
// ---------------------------------------------------------------------------
__global__ __launch_bounds__(256) void k_prepall(
    const float* __restrict__ w1, const float* __restrict__ b1,
    const float* __restrict__ w2, const float* __restrict__ b2,
    const float* __restrict__ w3, const float* __restrict__ w4,
    const float* __restrict__ cnw1, const float* __restrict__ epw1,
    const float* __restrict__ cnw2, const float* __restrict__ epw2,
    unsigned short* __restrict__ wpc, float* __restrict__ wcb,
    unsigned short* __restrict__ wp3, unsigned short* __restrict__ wp4,
    unsigned short* __restrict__ wph1, unsigned short* __restrict__ wpcn2,
    unsigned short* __restrict__ wpep2) {
    __shared__ float s_w1[800];
    __shared__ float s_w2[800];
    if (blockIdx.x < 32) {
        const int co = blockIdx.x, tid = threadIdx.x;
        for (int i = tid; i < 800; i += 256) {
            s_w1[i] = w1[i];
            s_w2[i] = w2[co * 800 + i];
        }
        __syncthreads();
        if (tid < 96) {
            int t = tid;
            float val = 0.f;
            if (t < 81) {
                int ty = t / 9, tx = t - 9 * ty;
                int ylo = ty > 4 ? ty - 4 : 0, yhi = ty < 4 ? ty : 4;
                int xlo = tx > 4 ? tx - 4 : 0, xhi = tx < 4 ? tx : 4;
                for (int k1y = ylo; k1y <= yhi; k1y++)
                    for (int k1x = xlo; k1x <= xhi; k1x++) {
                        int o1 = k1y * 5 + k1x;
                        int o2 = (ty - k1y) * 5 + (tx - k1x);
#pragma unroll
                        for (int ci = 0; ci < 32; ci++)
                            val += s_w1[ci * 25 + o1] * s_w2[ci * 25 + o2];
                    }
            }
            int n = co >> 1, nt = co & 1;
            int ks = t >> 5, r = t & 31, q = r >> 3, j = r & 7;
            wpc[ks * 1024 + nt * 512 + (q * 16 + n) * 8 + j] = f2bf(val);
        } else if (tid == 96) {
            float s = b2[co];
            for (int ci = 0; ci < 32; ci++) {
                float ws = 0.f;
#pragma unroll
                for (int t2 = 0; t2 < 25; t2++) ws += s_w2[ci * 25 + t2];
                s += b1[ci] * ws;
            }
            wcb[co] = s;
        }
        return;
    }
    int e = (blockIdx.x - 32) * 256 + threadIdx.x;
    if (e < 51200) {
        int j = e & 7, lane = (e >> 3) & 63, nt = (e >> 9) & 3, t = e >> 11;
        int co = 4 * (lane & 15) + nt, ci = (lane >> 4) * 8 + j;
        wp3[e] = f2bf(w3[(co * 32 + ci) * 25 + t]);
    } else if (e < 153600) {
        int e4 = e - 51200;
        int j = e4 & 7, lane = (e4 >> 3) & 63, nt = (e4 >> 9) & 3;
        int ks = (e4 >> 11) & 1, t = e4 >> 12;
        int co = 4 * (lane & 15) + nt, ci = ks * 32 + (lane >> 4) * 8 + j;
        wp4[e4] = f2bf(w4[(co * 64 + ci) * 25 + t]);
    } else {
        int eh = e - 153600;
        if (eh < 131072) {
            int j = eh & 7, lane = (eh >> 3) & 63, nt = (eh >> 9) & 31, kt = eh >> 14;
            int c = nt * 16 + (lane & 15);
            int k = kt * 32 + ((lane >> 4) << 3) + j;
            float v = (c < 256) ? cnw1[c * 256 + k] : epw1[(c - 256) * 256 + k];
            wph1[eh] = f2bf(v);
        } else if (eh < 163840) {
            int e2 = eh - 131072;
            int j = e2 & 7, lane = (e2 >> 3) & 63, nt = (e2 >> 9) & 7, kt = e2 >> 12;
            int c = nt * 16 + (lane & 15);
            int k = kt * 32 + ((lane >> 4) << 3) + j;
            wpcn2[e2] = f2bf(c < 120 ? cnw2[c * 256 + k] : 0.f);
        } else {
            int e3 = eh - 163840;
            int j = e3 & 7, lane = (e3 >> 3) & 63, idx = e3 >> 9;
            int kt = idx / 3, nt = idx - kt * 3;
            int c = nt * 16 + (lane & 15);
            int k = kt * 32 + ((lane >> 4) << 3) + j;
            wpep2[e3] = f2bf(c < 36 ? epw2[c * 256 + k] : 0.f);
        }
    }
}

// ---------------------------------------------------------------------------
// K_CONVALL: composite 9x9 conv (conv1∘conv2, K=81 pad 96) with in-register
// pooling, then conv3 + conv4 + pool + flatten (verified R13/R14). 512 thr.
// s_buf regions (ushort idx): p2 [144][40] @ [0,5760); s_c3 [64][72] @
// [5760,10368); s_c4 f32 [16][68] @ [0,2176) (p2 dead after conv3).
// ---------------------------------------------------------------------------
__global__ __launch_bounds__(512) void k_convall(
    const float* __restrict__ img,
    const unsigned short* __restrict__ wpc, const float* __restrict__ wcb,
    const unsigned short* __restrict__ wp3, const float* __restrict__ b3,
    const unsigned short* __restrict__ wp4, const float* __restrict__ b4,
    unsigned short* __restrict__ emb) {
    __shared__ __align__(16) unsigned short s_imgbf[32 * 36];
    __shared__ __align__(16) unsigned short s_buf[10368];
    const int b = blockIdx.x, tid = threadIdx.x;
    const int lane = tid & 63, wave = tid >> 6;
    const int m = lane & 15, quad = lane >> 4;
    const int C3O = 5760;

    // stage full image as bf16 (first 256 threads)
    if (tid < 256) {
        float4 t = ((const float4*)(img + (size_t)b * 1024))[tid];
        ushort4v pkv;
        pkv[0] = f2bf(t.x); pkv[1] = f2bf(t.y);
        pkv[2] = f2bf(t.z); pkv[3] = f2bf(t.w);
        *(ushort4v*)(s_imgbf + (tid >> 3) * 36 + (tid & 7) * 4) = pkv;
    }

    // composite-conv B-frags (held in regs all phase) + bias + tap offsets
    const short8* wqc = (const short8*)wpc;
    short8 cb0[3], cb1[3];
#pragma unroll
    for (int ks = 0; ks < 3; ks++) {
        cb0[ks] = wqc[(ks * 2 + 0) * 64 + lane];
        cb1[ks] = wqc[(ks * 2 + 1) * 64 + lane];
    }
    const float bc0 = wcb[2 * m], bc1 = wcb[2 * m + 1];
    int ct[3][8];
#pragma unroll
    for (int ks = 0; ks < 3; ks++)
#pragma unroll
        for (int j = 0; j < 8; j++) {
            int t = ks * 32 + quad * 8 + j;
            int toff = 0;
            if (t < 81) {
                int ty = (t * 57) >> 9;   // == t/9 for t<90
                toff = ty * 36 + (t - 9 * ty);
            }
            ct[ks][j] = toff;            // taps >=81 read garbage * B=0 -> 0
        }
    const short8* wq3 = (const short8*)wp3;

    __syncthreads();

    // ---- composite conv + in-register pool -> p2 [144][40] ----
    for (int T = wave; T < 36; T += 8) {
        int pg = T * 4 + (m >> 2);            // pooled output index 0..143
        int py = (pg * 171) >> 11;            // == pg/12 for pg<144
        int px = pg - py * 12;
        int wb = (2 * py + ((m & 3) >> 1)) * 36 + 2 * px + (m & 1);
        float4v a0 = {0.f, 0.f, 0.f, 0.f};
        float4v a1 = {0.f, 0.f, 0.f, 0.f};
#pragma unroll
        for (int ks = 0; ks < 3; ks++) {
            short8 av;
#pragma unroll
            for (int j = 0; j < 8; j++) av[j] = (short)s_imgbf[wb + ct[ks][j]];
            a0 = __builtin_amdgcn_mfma_f32_16x16x32_bf16(av, cb0[ks], a0, 0, 0, 0);
            a1 = __builtin_amdgcn_mfma_f32_16x16x32_bf16(av, cb1[ks], a1, 0, 0, 0);
        }
        float mx0 = fmaxf(fmaxf(a0[0], a0[1]), fmaxf(a0[2], a0[3])) + bc0;
        float mx1 = fmaxf(fmaxf(a1[0], a1[1]), fmaxf(a1[2], a1[3])) + bc1;
        int row = T * 4 + quad;
        *(unsigned*)(s_buf + row * 40 + 2 * m) = pk2(mx0, mx1);
    }
    __syncthreads();

    // ---- conv3: Mtile = wave>>1 (pos3 in 8x8 grid), Ntile half = wave&1 ----
    {
        int pos3 = (wave >> 1) * 16 + m;
        int y3 = pos3 >> 3, x3 = pos3 & 7;
        int a3 = (y3 * 12 + x3) * 40 + quad * 8;
        int nt0 = (wave & 1) * 2;
        float4v acc3[2];
        acc3[0] = (float4v){0.f, 0.f, 0.f, 0.f};
        acc3[1] = (float4v){0.f, 0.f, 0.f, 0.f};
        short8 bw3[2];
        bw3[0] = wq3[nt0 * 64 + lane];
        bw3[1] = wq3[(nt0 + 1) * 64 + lane];
        for (int t = 0; t < 25; t++) {
            short8 nb3[2];
            if (t < 24) {
                nb3[0] = wq3[((t + 1) * 4 + nt0) * 64 + lane];
                nb3[1] = wq3[((t + 1) * 4 + nt0 + 1) * 64 + lane];
            }
            const int ky = t / 5, kx = t - ky * 5;
            short8 av = *(const short8*)(s_buf + a3 + (ky * 12 + kx) * 40);
            acc3[0] = __builtin_amdgcn_mfma_f32_16x16x32_bf16(av, bw3[0], acc3[0], 0, 0, 0);
            acc3[1] = __builtin_amdgcn_mfma_f32_16x16x32_bf16(av, bw3[1], acc3[1], 0, 0, 0);
            if (t < 24) { bw3[0] = nb3[0]; bw3[1] = nb3[1]; }
        }
        float bb0 = b3[4 * m + nt0], bb1 = b3[4 * m + nt0 + 1];
#pragma unroll
        for (int r = 0; r < 4; r++) {
            int row3 = (wave >> 1) * 16 + quad * 4 + r;
            *(unsigned*)(s_buf + C3O + row3 * 72 + 4 * m + nt0) =
                pk2(acc3[0][r] + bb0, acc3[1][r] + bb1);
        }
    }
    __syncthreads();

    // ---- conv4: waves 0-3 (Ntile = wave, 2 Ksteps); waves 4-7 idle ----
    if (wave < 4) {
        int y4 = m >> 2, x4 = m & 3;
        int a4 = C3O + (y4 * 8 + x4) * 72 + quad * 8;
        float4v acc4 = (float4v){0.f, 0.f, 0.f, 0.f};
        const short8* wq4 = (const short8*)wp4;
        short8 cw0 = wq4[(0 * 4 + wave) * 64 + lane];
        short8 cw1 = wq4[(1 * 4 + wave) * 64 + lane];
        for (int t = 0; t < 25; t++) {
            short8 n0, n1;
            if (t < 24) {
                n0 = wq4[(((t + 1) * 2) * 4 + wave) * 64 + lane];
                n1 = wq4[(((t + 1) * 2 + 1) * 4 + wave) * 64 + lane];
            }
            const int ky = t / 5, kx = t - ky * 5;
            const int toff = (ky * 8 + kx) * 72;
            short8 av0 = *(const short8*)(s_buf + a4 + toff);
            acc4 = __builtin_amdgcn_mfma_f32_16x16x32_bf16(av0, cw0, acc4, 0, 0, 0);
            short8 av1 = *(const short8*)(s_buf + a4 + toff + 32);
            acc4 = __builtin_amdgcn_mfma_f32_16x16x32_bf16(av1, cw1, acc4, 0, 0, 0);
            if (t < 24) { cw0 = n0; cw1 = n1; }
        }
        float* s_c4 = (float*)s_buf;
#pragma unroll
        for (int r = 0; r < 4; r++)
            s_c4[(quad * 4 + r) * 68 + 4 * m + wave] = acc4[r];
    }
    __syncthreads();

    // emb epilogue: tid = co*4 + pp; pool 2x2 + bias4 + flatten
    if (tid < 256) {
        const float* s_c4 = (const float*)s_buf;
        int co = tid >> 2, pp = tid & 3;
        int ppy = pp >> 1, ppx = pp & 1;
        float v0 = s_c4[((2 * ppy) * 4 + 2 * ppx) * 68 + co];
        float v1 = s_c4[((2 * ppy) * 4 + 2 * ppx + 1) * 68 + co];
        float v2 = s_c4[((2 * ppy + 1) * 4 + 2 * ppx) * 68 + co];
        float v3 = s_c4[((2 * ppy + 1) * 4 + 2 * ppx + 1) * 68 + co];
        emb[(size_t)b * 256 + tid] =
            f2bf(fmaxf(fmaxf(v0, v1), fmaxf(v2, v3)) + b4[co]);
    }
}

// ---------------------------------------------------------------------------
// K5: fused heads (MFMA) + DAMP recurrence (verified R4-R14, unchanged).
// ---------------------------------------------------------------------------
__global__ __launch_bounds__(256) void k_heads(
    const unsigned short* __restrict__ emb,
    const unsigned short* __restrict__ wph1,
    const float* __restrict__ cn_b1, const float* __restrict__ ep_b1,
    const unsigned short* __restrict__ wpcn2, const float* __restrict__ cn_b2,
    const unsigned short* __restrict__ wpep2, const float* __restrict__ ep_b2,
    float* __restrict__ out) {
    __shared__ unsigned short s_hid[16 * 520];
    __shared__ float s_conn[120 * 17];
    __shared__ float s_rec0[120 * 17];
    __shared__ float s_rec1[120 * 17];
    __shared__ float s_ep[36 * 17];
    const int tid = threadIdx.x;
    const int lane = tid & 63, wave = tid >> 6;
    const int m = lane & 15, q = lane >> 4;
    const int b0 = blockIdx.x * 16;

    float4v acc[8];
#pragma unroll
    for (int i = 0; i < 8; i++) acc[i] = (float4v){0.f, 0.f, 0.f, 0.f};
    const short8* wp1 = (const short8*)wph1;
    for (int kt = 0; kt < 8; kt++) {
        short8 av = *(const short8*)(emb + (size_t)(b0 + m) * 256 + kt * 32 + q * 8);
#pragma unroll
        for (int ntl = 0; ntl < 8; ntl++) {
            int nt = wave * 8 + ntl;
            short8 bv = wp1[(kt * 32 + nt) * 64 + lane];
            acc[ntl] = __builtin_amdgcn_mfma_f32_16x16x32_bf16(av, bv, acc[ntl], 0, 0, 0);
        }
    }
#pragma unroll
    for (int ntl = 0; ntl < 8; ntl++) {
        int c = (wave * 8 + ntl) * 16 + m;
        float bb = (c < 256) ? cn_b1[c] : ep_b1[c - 256];
#pragma unroll
        for (int r = 0; r < 4; r++)
            s_hid[(q * 4 + r) * 520 + c] = f2bf(fmaxf(acc[ntl][r] + bb, 0.f));
    }
    __syncthreads();

    for (int job = wave; job < 11; job += 4) {
        const bool isconn = job < 8;
        const int koff = isconn ? 0 : 256;
        float4v a2 = (float4v){0.f, 0.f, 0.f, 0.f};
        for (int kt = 0; kt < 8; kt++) {
            short8 av = *(const short8*)(s_hid + m * 520 + koff + kt * 32 + q * 8);
            short8 bv = isconn
                ? ((const short8*)wpcn2)[(kt * 8 + job) * 64 + lane]
                : ((const short8*)wpep2)[(kt * 3 + (job - 8)) * 64 + lane];
            a2 = __builtin_amdgcn_mfma_f32_16x16x32_bf16(av, bv, a2, 0, 0, 0);
        }
        int c = (isconn ? job : (job - 8)) * 16 + m;
        float bb = isconn ? (c < 120 ? cn_b2[c] : 0.f) : (c < 36 ? ep_b2[c] : 0.f);
#pragma unroll
        for (int r = 0; r < 4; r++) {
            float v = 1.f / (1.f + __expf(-(a2[r] + bb)));
            int row = q * 4 + r;
            if (isconn) {
                if (c < 120) { s_conn[c * 17 + row] = v; s_rec0[c * 17 + row] = v; }
            } else {
                if (c < 36) s_ep[c * 17 + row] = v;
            }
        }
    }
    __syncthreads();

    const int row = tid >> 4, g = tid & 15;
    const int ns = G16_START[g];
    const int nodecnt = G16_START[g + 1] - ns;
    int ie[3][4], icnt[3], os[3], oc[3];
    float cr[3][4];
#pragma unroll
    for (int s = 0; s < 3; s++) {
        if (s < nodecnt) {
            int n = ns + s;
            icnt[s] = ADJC.cnt[n];
#pragma unroll
            for (int qx = 0; qx < 4; qx++) ie[s][qx] = ADJC.idx[n][qx];
            os[s] = ADJC.ostart[n];
            oc[s] = ADJC.ocnt[n];
#pragma unroll
            for (int oe = 0; oe < 4; oe++)
                cr[s][oe] = (oe < oc[s]) ? s_conn[(os[s] + oe) * 17 + row] : 0.f;
        } else {
            icnt[s] = 0; oc[s] = 0; os[s] = 0;
#pragma unroll
            for (int qx = 0; qx < 4; qx++) ie[s][qx] = 0;
#pragma unroll
            for (int oe = 0; oe < 4; oe++) cr[s][oe] = 0.f;
        }
    }
    float old0 = (g == 0) ? s_conn[0 * 17 + row] : 0.f;

    for (int it = 0; it < 36; it++) {
        const float* cur = (it & 1) ? s_rec1 : s_rec0;
        float* nxt = (it & 1) ? s_rec0 : s_rec1;
#pragma unroll
        for (int s = 0; s < 3; s++) {
            float sum = 0.f;
#pragma unroll
            for (int qx = 0; qx < 4; qx++)
                sum += (qx < icnt[s]) ? cur[ie[s][qx] * 17 + row] : 0.f;
            sum = fminf(sum, 1.f);
#pragma unroll
            for (int oe = 0; oe < 4; oe++) {
                if (oe < oc[s]) {
                    int e = os[s] + oe;
                    float nv = sum * cr[s][oe];
                    nxt[e * 17 + row] = nv;
                    if (g == 0 && s == 0 && oe == 0)
                        old0 = fminf(old0 + nv, 1.f);
                }
            }
        }
        __asm__ volatile("s_waitcnt lgkmcnt(0)" ::: "memory");
    }

    if (g == 0)
        out[b0 + row] = old0 * s_ep[0 * 17 + row] * s_ep[6 * 17 + row];
}

// ---------------------------------------------------------------------------
extern "C" void kernel_launch(void* const* d_in, const int* in_sizes, int n_in,
                              void* d_out, int out_size, void* d_ws, size_t ws_size,
                              hipStream_t stream) {
    const float* image = (const float*)d_in[0];
    const float* c1w = (const float*)d_in[1];
    const float* c1b = (const float*)d_in[2];
    const float* c2w = (const float*)d_in[3];
    const float* c2b = (const float*)d_in[4];
    const float* c3w = (const float*)d_in[5];
    const float* c3b = (const float*)d_in[6];
    const float* c4w = (const float*)d_in[7];
    const float* c4b = (const float*)d_in[8];
    const float* epw1 = (const float*)d_in[9];
    const float* epb1 = (const float*)d_in[10];
    const float* epw2 = (const float*)d_in[11];
    const float* epb2 = (const float*)d_in[12];
    const float* cnw1 = (const float*)d_in[13];
    const float* cnb1 = (const float*)d_in[14];
    const float* cnw2 = (const float*)d_in[15];
    const float* cnb2 = (const float*)d_in[16];

    const int B = in_sizes[0] / (32 * 32);  // 1024

    unsigned short* ws = (unsigned short*)d_ws;
    unsigned short* embo = ws;                            // B*256 bf16
    unsigned short* wp3 = embo + (size_t)B * 256;         // 51200
    unsigned short* wp4 = wp3 + 51200;                    // 102400
    unsigned short* wph1 = wp4 + 102400;                  // 131072
    unsigned short* wpcn2 = wph1 + 131072;                // 32768
    unsigned short* wpep2 = wpcn2 + 32768;                // 12288
    unsigned short* wpc = wpep2 + 12288;                  // 3072
    float* wcb = (float*)(wpc + 3072);                    // 32 f32

    k_prepall<<<1320, 256, 0, stream>>>(c1w, c1b, c2w, c2b, c3w, c4w,
                                        cnw1, epw1, cnw2, epw2,
                                        wpc, wcb, wp3, wp4, wph1, wpcn2, wpep2);
    k_convall<<<B, 512, 0, stream>>>(image, wpc, wcb, wp3, c3b, wp4, c4b, embo);
    k_heads<<<B / 16, 256, 0, stream>>>(embo, wph1, cnb1, epb1,
                                        wpcn2, cnb2, wpep2, epb2, (float*)d_out);
}